// Round 1
// baseline (931.120 us; speedup 1.0000x reference)
//
#include <hip/hip_runtime.h>

// Problem constants (B,C,H,W = 2,64,48,48; nh=8 -> d=8, L=2304)
#define LL   2304
#define CCH  64
#define NHD  8
#define NB   1024   // persistent grid: 4 blocks/CU x 256 CUs, all co-resident

static constexpr float QSCALE = 0.35355339059327373f;  // 8^-0.5
static constexpr float LOG2E  = 1.4426950408889634f;

typedef _Float16 half2_t  __attribute__((ext_vector_type(2)));
typedef _Float16 half4_t  __attribute__((ext_vector_type(4)));
typedef _Float16 half8_t  __attribute__((ext_vector_type(8)));
typedef float    float16_t __attribute__((ext_vector_type(16)));

__device__ __forceinline__ half2_t pk_f16(float a, float b) {
    return __builtin_bit_cast(half2_t, __builtin_amdgcn_cvt_pkrtz(a, b));
}

// ---------------------------------------------------------------------------
// Device-wide barrier for a fully-resident grid of NB blocks.
// Generation-counting: no reset needed across graph replays (__device__
// globals persist; gGen grows monotonically). Agent-scope atomics +
// __threadfence give cross-XCD release/acquire (per-XCD L2s not coherent).
// ---------------------------------------------------------------------------
__device__ unsigned gCnt = 0, gGen = 0;

__device__ __forceinline__ void grid_sync() {
    __threadfence();      // release this block's global writes (L2 wb)
    __syncthreads();
    if (threadIdx.x == 0) {
        unsigned g = __hip_atomic_load(&gGen, __ATOMIC_RELAXED, __HIP_MEMORY_SCOPE_AGENT);
        unsigned v = __hip_atomic_fetch_add(&gCnt, 1u, __ATOMIC_ACQ_REL, __HIP_MEMORY_SCOPE_AGENT);
        if (v == NB - 1) {
            __hip_atomic_store(&gCnt, 0u, __ATOMIC_RELAXED, __HIP_MEMORY_SCOPE_AGENT);
            __hip_atomic_fetch_add(&gGen, 1u, __ATOMIC_RELEASE, __HIP_MEMORY_SCOPE_AGENT);
        } else {
            while (__hip_atomic_load(&gGen, __ATOMIC_ACQUIRE, __HIP_MEMORY_SCOPE_AGENT) == g)
                __builtin_amdgcn_s_sleep(2);
        }
    }
    __syncthreads();
    __threadfence();      // acquire: invalidate stale L1/L2 before reading
}

// v_mfma_f32_32x32x8_f16 lane maps (K=8):
//   A[m = lane&31][k = (lane>>5)*4 + j]   (half4 per lane)
//   B[k = (lane>>5)*4 + j][n = lane&31]
//   C/D: col = lane&31, row = (reg&3) + 8*(reg>>2) + 4*(lane>>5)

// ---------------------------------------------------------------------------
// Single persistent kernel: 4 phases separated by grid_sync().
//   P1 qkv   (432 units: ltile x b x mat)   -> qout, Qt, Kt, Vt
//   P2 denom (1152 units: ktile x bh)       -> V2 = V^T * 256/D
//   P3 av    (1152 units: qblk x bh x kspl) -> ot partial slabs
//   P4 out   (144 units: ltile x b)         -> out
// LDS: phases overlay the same 24KB arena (max = 24576B). 24KB*4 = 96KB/CU.
// ---------------------------------------------------------------------------
__global__ __launch_bounds__(256, 4) void k_fused(
    const float* __restrict__ x,
    const float* __restrict__ Wq, const float* __restrict__ bq,
    const float* __restrict__ Wk, const float* __restrict__ bk,
    const float* __restrict__ Wv, const float* __restrict__ bv,
    const float* __restrict__ Wo, const float* __restrict__ bo,
    float* __restrict__ qout, float* __restrict__ out,
    _Float16* __restrict__ Qt, _Float16* __restrict__ Kt, _Float16* __restrict__ Vt,
    _Float16* __restrict__ V2, float* __restrict__ ot)
{
    __shared__ __align__(16) char smraw[24576];
    const int t   = threadIdx.x;
    const int bid = blockIdx.x;

    // ======================= Phase 1: q/k/v conv1x1 =======================
    {
        const int u0 = (432 * bid) / NB, u1 = (432 * (bid + 1)) / NB;  // 0..1 units
        float (*xs)[32]  = (float(*)[32])smraw;            // [64][32] 8KB
        float (*wsm)[64] = (float(*)[64])(smraw + 8192);   // [64][64] 16KB
        for (int u = u0; u < u1; ++u) {
            const int mat = u / 144, rem = u - mat * 144;
            const int b = rem / 72, l0 = (rem % 72) * 32;
            const float* W    = (mat == 0) ? Wq : (mat == 1 ? Wk : Wv);
            const float* bias = (mat == 0) ? bq : (mat == 1 ? bk : bv);
            const float* xb = x + (long)b * CCH * LL;

            #pragma unroll
            for (int p = 0; p < 2; ++p) {
                int flat = (p * 256 + t) * 4;
                int c = flat >> 5, l = flat & 31;
                *(float4*)&xs[c][l] = *(const float4*)&xb[(long)c * LL + l0 + l];
            }
            #pragma unroll
            for (int p = 0; p < 4; ++p) {
                int flat = (p * 256 + t) * 4;
                int c = flat >> 6, l = flat & 63;
                *(float4*)&wsm[c][l] = *(const float4*)&W[flat];
            }
            __syncthreads();

            const int l  = t & 31;
            const int cg = t >> 5;  // head 0..7
            float acc[8];
            #pragma unroll
            for (int j = 0; j < 8; ++j) acc[j] = 0.f;
            for (int cp = 0; cp < 64; ++cp) {
                float xv = xs[cp][l];
                #pragma unroll
                for (int j = 0; j < 8; ++j) acc[j] = fmaf(wsm[cg * 8 + j][cp], xv, acc[j]);
            }
            long row = (long)(b * NHD + cg) * LL + l0 + l;
            if (mat == 0) {
                half8_t pq;
                #pragma unroll
                for (int j = 0; j < 8; ++j) {
                    float qv = (acc[j] + bias[cg * 8 + j]) * QSCALE;
                    qout[((long)b * CCH + cg * 8 + j) * LL + l0 + l] = qv;
                    pq[j] = (_Float16)(qv * LOG2E);
                }
                *(half8_t*)(Qt + row * 8) = pq;
            } else if (mat == 1) {
                half8_t pk;
                #pragma unroll
                for (int j = 0; j < 8; ++j) pk[j] = (_Float16)(acc[j] + bias[cg * 8 + j]);
                *(half8_t*)(Kt + row * 8) = pk;
            } else {
                half8_t pv;
                #pragma unroll
                for (int j = 0; j < 8; ++j) pv[j] = (_Float16)(acc[j] + bias[cg * 8 + j]);
                *(half8_t*)(Vt + row * 8) = pv;
            }
        }
    }
    grid_sync();

    // ================ Phase 2: D[k] = sum_q 2^(Q'.K), V2 =================
    {
        const int u0 = (1152 * bid) / NB, u1 = (1152 * (bid + 1)) / NB;  // 1..2 units
        _Float16 (*lQ)[256][4] = (_Float16(*)[256][4])smraw;   // [2][256][4] 4KB
        float (*Dp)[32] = (float(*)[32])(smraw + 4096);        // [4][32]
        float *rDs      = (float*)(smraw + 4608);              // [32]
        const int lane = t & 63, w = t >> 6;
        const int half = lane >> 5, l31 = lane & 31;

        for (int u = u0; u < u1; ++u) {
            const int bh = u / 72, k0 = (u - bh * 72) * 32;
            half4_t kA = *(const half4_t*)(Kt + ((long)bh * LL + k0 + l31) * 8 + half * 4);
            const float4* qbase = (const float4*)(Qt + (long)bh * LL * 8);
            float4 pre = qbase[t];

            float16_t Dacc = {};
            for (int ch = 0; ch < 9; ++ch) {
                __syncthreads();
                *(float2*)&lQ[0][t][0] = make_float2(pre.x, pre.y);   // d 0..3
                *(float2*)&lQ[1][t][0] = make_float2(pre.z, pre.w);   // d 4..7
                __syncthreads();
                if (ch + 1 < 9) pre = qbase[(ch + 1) * 256 + t];
                #pragma unroll
                for (int T = 0; T < 2; ++T) {
                    half4_t qB = *(const half4_t*)&lQ[half][(2 * w + T) * 32 + l31][0];
                    float16_t S = __builtin_amdgcn_mfma_f32_32x32x8f16(kA, qB, (float16_t){}, 0, 0, 0);
                    #pragma unroll
                    for (int r = 0; r < 16; ++r) Dacc[r] += __builtin_amdgcn_exp2f(S[r]);
                }
            }
            #pragma unroll
            for (int r = 0; r < 16; ++r) {
                float v = Dacc[r];
                v += __shfl_xor(v, 1);  v += __shfl_xor(v, 2);  v += __shfl_xor(v, 4);
                v += __shfl_xor(v, 8);  v += __shfl_xor(v, 16);
                Dacc[r] = v;
            }
            if (l31 == 0) {
                #pragma unroll
                for (int r = 0; r < 16; ++r) {
                    int row = (r & 3) + 8 * (r >> 2) + 4 * half;
                    Dp[w][row] = Dacc[r];
                }
            }
            __syncthreads();
            if (t < 32) rDs[t] = 256.0f / (Dp[0][t] + Dp[1][t] + Dp[2][t] + Dp[3][t]);
            __syncthreads();
            {   // V2[bh][c][k0+kk] = V[k0+kk][c] * rDs[kk]
                int kk = t >> 3, c = t & 7;
                float v = (float)Vt[((long)bh * LL + k0 + kk) * 8 + c];
                V2[((long)bh * 8 + c) * LL + k0 + kk] = (_Float16)(v * rDs[kk]);
            }
        }
    }
    grid_sync();

    // ===================== Phase 3: O' = V2 . 2^(Q'.K) ====================
    {
        const int u0 = (1152 * bid) / NB, u1 = (1152 * (bid + 1)) / NB;
        _Float16 (*lK)[64][4] = (_Float16(*)[64][4])smraw;          // [2][64][4] 1KB
        _Float16 (*lVt)[72]   = (_Float16(*)[72])(smraw + 1024);    // [8][72]
        const int lane = t & 63, w = t >> 6;
        const int half = lane >> 5, l31 = lane & 31;

        for (int u = u0; u < u1; ++u) {
            const int qb = u % 18, rem2 = u / 18;
            const int bh = rem2 & 15, s = rem2 >> 4;
            const int b = bh >> 3, h = bh & 7;
            const int q0 = qb * 128 + w * 32;

            half4_t qB = *(const half4_t*)(Qt + ((long)bh * LL + q0 + l31) * 8 + half * 4);
            const long ks0 = (long)s * 576;
            const float4*    kbase = (const float4*)(Kt + ((long)bh * LL + ks0) * 8);
            const _Float16*  vbase = V2 + (long)bh * 8 * LL + ks0;

            float4 preK, preV;
            if (t < 64) preK = kbase[t];
            else if (t < 128) {
                int c = (t - 64) >> 3, j8 = (t - 64) & 7;
                preV = *(const float4*)(vbase + (long)c * LL + j8 * 8);
            }

            float16_t O = {};
            for (int ch = 0; ch < 9; ++ch) {
                __syncthreads();
                if (t < 64) {
                    *(float2*)&lK[0][t][0] = make_float2(preK.x, preK.y);
                    *(float2*)&lK[1][t][0] = make_float2(preK.z, preK.w);
                } else if (t < 128) {
                    int c = (t - 64) >> 3, j8 = (t - 64) & 7;
                    *(float4*)&lVt[c][j8 * 8] = preV;
                }
                __syncthreads();
                if (ch + 1 < 9) {
                    if (t < 64) preK = kbase[(ch + 1) * 64 + t];
                    else if (t < 128) {
                        int c = (t - 64) >> 3, j8 = (t - 64) & 7;
                        preV = *(const float4*)(vbase + (long)c * LL + (ch + 1) * 64 + j8 * 8);
                    }
                }
                const int cl = l31 & 7;   // lanes 8..31 duplicate c rows (D rows >=8 unused)
                #pragma unroll
                for (int T = 0; T < 2; ++T) {
                    int kb = T * 32;
                    half4_t kA = *(const half4_t*)&lK[half][kb + l31][0];
                    float16_t S = __builtin_amdgcn_mfma_f32_32x32x8f16(kA, qB, (float16_t){}, 0, 0, 0);
                    #pragma unroll
                    for (int g = 0; g < 4; ++g) {
                        half2_t p0 = pk_f16(__builtin_amdgcn_exp2f(S[4 * g + 0]),
                                            __builtin_amdgcn_exp2f(S[4 * g + 1]));
                        half2_t p1 = pk_f16(__builtin_amdgcn_exp2f(S[4 * g + 2]),
                                            __builtin_amdgcn_exp2f(S[4 * g + 3]));
                        half4_t pB = __builtin_shufflevector(p0, p1, 0, 1, 2, 3);
                        half4_t vA = *(const half4_t*)&lVt[cl][kb + g * 8 + half * 4];
                        O = __builtin_amdgcn_mfma_f32_32x32x8f16(vA, pB, O, 0, 0, 0);
                    }
                }
            }
            // rows c<8 live in regs 0..3: c = r + 4*half; col q = l31
            float* otb = ot + (long)s * (2 * CCH * LL) + ((long)b * CCH + h * 8) * LL;
            #pragma unroll
            for (int r = 0; r < 4; ++r) {
                int c = r + 4 * half;
                otb[(long)c * LL + q0 + l31] = O[r] * (1.0f / 256.0f);
            }
        }
    }
    grid_sync();

    // ==================== Phase 4: out = Wo.(sum ot) + bo =================
    {
        const int u0 = (144 * bid) / NB, u1 = (144 * (bid + 1)) / NB;  // 0..1 units
        float (*os)[32]  = (float(*)[32])smraw;
        float (*wsm)[64] = (float(*)[64])(smraw + 8192);
        const long SLAB = 2 * CCH * (long)LL;
        for (int u = u0; u < u1; ++u) {
            const int b = u / 72, l0 = (u % 72) * 32;
            const float* ob = ot + (long)b * CCH * LL;

            #pragma unroll
            for (int p = 0; p < 2; ++p) {
                int flat = (p * 256 + t) * 4;
                int cv = flat >> 5, l = flat & 31;
                long off = (long)cv * LL + l0 + l;
                float4 a = *(const float4*)&ob[off];
                #pragma unroll
                for (int s = 1; s < 4; ++s) {
                    float4 bb = *(const float4*)&ob[s * SLAB + off];
                    a.x += bb.x; a.y += bb.y; a.z += bb.z; a.w += bb.w;
                }
                *(float4*)&os[cv][l] = a;
            }
            #pragma unroll
            for (int p = 0; p < 4; ++p) {
                int flat = (p * 256 + t) * 4;
                int c = flat >> 6, l = flat & 63;
                *(float4*)&wsm[c][l] = *(const float4*)&Wo[flat];
            }
            __syncthreads();

            const int l  = t & 31;
            const int cg = t >> 5;
            float acc[8];
            #pragma unroll
            for (int j = 0; j < 8; ++j) acc[j] = 0.f;
            for (int cv = 0; cv < 64; ++cv) {
                float xv = os[cv][l];
                #pragma unroll
                for (int j = 0; j < 8; ++j) acc[j] = fmaf(wsm[cg * 8 + j][cv], xv, acc[j]);
            }
            #pragma unroll
            for (int j = 0; j < 8; ++j) {
                int co = cg * 8 + j;
                out[((long)b * CCH + co) * LL + l0 + l] = acc[j] + bo[co];
            }
        }
    }
}

// ---------------------------------------------------------------------------
extern "C" void kernel_launch(void* const* d_in, const int* in_sizes, int n_in,
                              void* d_out, int out_size, void* d_ws, size_t ws_size,
                              hipStream_t stream)
{
    const float* x  = (const float*)d_in[0];
    const float* Wq = (const float*)d_in[1];
    const float* bq = (const float*)d_in[2];
    const float* Wk = (const float*)d_in[3];
    const float* bk = (const float*)d_in[4];
    const float* Wv = (const float*)d_in[5];
    const float* bv = (const float*)d_in[6];
    const float* Wo = (const float*)d_in[7];
    const float* bo = (const float*)d_in[8];

    float* out  = (float*)d_out;          // [2][64][2304]
    float* qout = out + 294912;           // second tuple output: scaled q

    // ws: 4 f16 buffers (576KB ea) + 4 f32 ot slabs (4.7MB) = 7.08 MB
    _Float16* Qt = (_Float16*)d_ws;       // [16][2304][8] f16, * log2e*d^-0.5
    _Float16* Kt = Qt + 294912;           // [16][2304][8] f16
    _Float16* Vt = Kt + 294912;           // [16][2304][8] f16 (raw V)
    _Float16* V2 = Vt + 294912;           // [16][8][2304] f16 = V^T * 256/D
    float*    ot = (float*)(V2 + 294912); // [4][2][64][2304] f32 partial slabs

    k_fused<<<dim3(NB), 256, 0, stream>>>(x, Wq, bq, Wk, bk, Wv, bv, Wo, bo,
                                          qout, out, Qt, Kt, Vt, V2, ot);
}

// Round 2
// 168.855 us; speedup vs baseline: 5.5143x; 5.5143x over previous
//
#include <hip/hip_runtime.h>

// Problem constants (B,C,H,W = 2,64,48,48; nh=8 -> d=8, L=2304)
#define LL   2304
#define CCH  64
#define NHD  8
#define NB   576    // persistent grid: <=4 blocks/CU guaranteed co-resident

static constexpr float QSCALE = 0.35355339059327373f;  // 8^-0.5
static constexpr float LOG2E  = 1.4426950408889634f;

typedef _Float16 half2_t  __attribute__((ext_vector_type(2)));
typedef _Float16 half4_t  __attribute__((ext_vector_type(4)));
typedef _Float16 half8_t  __attribute__((ext_vector_type(8)));
typedef float    float16_t __attribute__((ext_vector_type(16)));

__device__ __forceinline__ half2_t pk_f16(float a, float b) {
    return __builtin_bit_cast(half2_t, __builtin_amdgcn_cvt_pkrtz(a, b));
}

// ---------------------------------------------------------------------------
// Cheap device-wide barrier for a fully-resident grid of NB blocks.
// Design rules (round-1 post-mortem: acquire-spin = buffer_inv storm = 885us):
//  - spin on RELAXED agent loads (no cache-maintenance per poll) + s_sleep
//  - exactly ONE release (wbL2) per block: the RELEASE fetch_add arrival
//  - exactly ONE acquire (inv) per block: a single ACQUIRE load at exit
//  - 8 padded sub-counters cut same-cacheline RMW serialization
// Generation counter survives graph replays (device globals persist).
// ---------------------------------------------------------------------------
struct alignas(128) PadCtr { unsigned v; unsigned pad[31]; };
__device__ PadCtr   gSub[8];     // zero-init
__device__ unsigned gMaster = 0;
__device__ unsigned gGen = 0;

__device__ __forceinline__ void grid_sync() {
    __syncthreads();
    if (threadIdx.x == 0) {
        const int sub = blockIdx.x & 7;          // NB % 8 == 0: quota 72 each
        unsigned g = __hip_atomic_load(&gGen, __ATOMIC_RELAXED, __HIP_MEMORY_SCOPE_AGENT);
        // release-arrive: the RELEASE RMW emits one buffer_wbl2 for this
        // block's phase writes, then the add at the coherence point.
        unsigned v = __hip_atomic_fetch_add(&gSub[sub].v, 1u, __ATOMIC_RELEASE,
                                            __HIP_MEMORY_SCOPE_AGENT);
        if (v == (NB / 8) - 1) {
            unsigned m = __hip_atomic_fetch_add(&gMaster, 1u, __ATOMIC_RELAXED,
                                                __HIP_MEMORY_SCOPE_AGENT);
            if (m == 7) {
                #pragma unroll
                for (int i = 0; i < 8; ++i)
                    __hip_atomic_store(&gSub[i].v, 0u, __ATOMIC_RELAXED, __HIP_MEMORY_SCOPE_AGENT);
                __hip_atomic_store(&gMaster, 0u, __ATOMIC_RELAXED, __HIP_MEMORY_SCOPE_AGENT);
                __hip_atomic_store(&gGen, g + 1u, __ATOMIC_RELEASE, __HIP_MEMORY_SCOPE_AGENT);
            }
        }
        // relaxed spin: plain coherence-point loads, no invalidates
        while (__hip_atomic_load(&gGen, __ATOMIC_RELAXED, __HIP_MEMORY_SCOPE_AGENT) == g)
            __builtin_amdgcn_s_sleep(8);
        // single acquire: one L2 invalidate so this block reads fresh data
        (void)__hip_atomic_load(&gGen, __ATOMIC_ACQUIRE, __HIP_MEMORY_SCOPE_AGENT);
    }
    __syncthreads();
}

// v_mfma_f32_32x32x8_f16 lane maps (K=8):
//   A[m = lane&31][k = (lane>>5)*4 + j]   (half4 per lane)
//   B[k = (lane>>5)*4 + j][n = lane&31]
//   C/D: col = lane&31, row = (reg&3) + 8*(reg>>2) + 4*(lane>>5)

// ---------------------------------------------------------------------------
// Single persistent kernel: 4 phases separated by grid_sync().
//   P1 qkv   (432 units)  -> qout, Qt, Kt, Vt
//   P2 denom (1152 units = 2/block) -> V2 = V^T * 256/D
//   P3 av    (1152 units = 2/block) -> ot partial slabs
//   P4 out   (144 units)  -> out
// LDS: phases overlay one 24KB arena.
// ---------------------------------------------------------------------------
__global__ __launch_bounds__(256, 4) void k_fused(
    const float* __restrict__ x,
    const float* __restrict__ Wq, const float* __restrict__ bq,
    const float* __restrict__ Wk, const float* __restrict__ bk,
    const float* __restrict__ Wv, const float* __restrict__ bv,
    const float* __restrict__ Wo, const float* __restrict__ bo,
    float* __restrict__ qout, float* __restrict__ out,
    _Float16* __restrict__ Qt, _Float16* __restrict__ Kt, _Float16* __restrict__ Vt,
    _Float16* __restrict__ V2, float* __restrict__ ot)
{
    __shared__ __align__(16) char smraw[24576];
    const int t   = threadIdx.x;
    const int bid = blockIdx.x;

    // ======================= Phase 1: q/k/v conv1x1 =======================
    {
        const int u0 = (432 * bid) / NB, u1 = (432 * (bid + 1)) / NB;  // 0..1 units
        float (*xs)[32]  = (float(*)[32])smraw;            // [64][32] 8KB
        float (*wsm)[64] = (float(*)[64])(smraw + 8192);   // [64][64] 16KB
        for (int u = u0; u < u1; ++u) {
            const int mat = u / 144, rem = u - mat * 144;
            const int b = rem / 72, l0 = (rem % 72) * 32;
            const float* W    = (mat == 0) ? Wq : (mat == 1 ? Wk : Wv);
            const float* bias = (mat == 0) ? bq : (mat == 1 ? bk : bv);
            const float* xb = x + (long)b * CCH * LL;

            #pragma unroll
            for (int p = 0; p < 2; ++p) {
                int flat = (p * 256 + t) * 4;
                int c = flat >> 5, l = flat & 31;
                *(float4*)&xs[c][l] = *(const float4*)&xb[(long)c * LL + l0 + l];
            }
            #pragma unroll
            for (int p = 0; p < 4; ++p) {
                int flat = (p * 256 + t) * 4;
                int c = flat >> 6, l = flat & 63;
                *(float4*)&wsm[c][l] = *(const float4*)&W[flat];
            }
            __syncthreads();

            const int l  = t & 31;
            const int cg = t >> 5;  // head 0..7
            float acc[8];
            #pragma unroll
            for (int j = 0; j < 8; ++j) acc[j] = 0.f;
            for (int cp = 0; cp < 64; ++cp) {
                float xv = xs[cp][l];
                #pragma unroll
                for (int j = 0; j < 8; ++j) acc[j] = fmaf(wsm[cg * 8 + j][cp], xv, acc[j]);
            }
            long row = (long)(b * NHD + cg) * LL + l0 + l;
            if (mat == 0) {
                half8_t pq;
                #pragma unroll
                for (int j = 0; j < 8; ++j) {
                    float qv = (acc[j] + bias[cg * 8 + j]) * QSCALE;
                    qout[((long)b * CCH + cg * 8 + j) * LL + l0 + l] = qv;
                    pq[j] = (_Float16)(qv * LOG2E);
                }
                *(half8_t*)(Qt + row * 8) = pq;
            } else if (mat == 1) {
                half8_t pk;
                #pragma unroll
                for (int j = 0; j < 8; ++j) pk[j] = (_Float16)(acc[j] + bias[cg * 8 + j]);
                *(half8_t*)(Kt + row * 8) = pk;
            } else {
                half8_t pv;
                #pragma unroll
                for (int j = 0; j < 8; ++j) pv[j] = (_Float16)(acc[j] + bias[cg * 8 + j]);
                *(half8_t*)(Vt + row * 8) = pv;
            }
        }
    }
    grid_sync();

    // ================ Phase 2: D[k] = sum_q 2^(Q'.K), V2 =================
    {
        const int u0 = (1152 * bid) / NB, u1 = (1152 * (bid + 1)) / NB;  // 2 units
        _Float16 (*lQ)[256][4] = (_Float16(*)[256][4])smraw;   // [2][256][4] 4KB
        float (*Dp)[32] = (float(*)[32])(smraw + 4096);        // [4][32]
        float *rDs      = (float*)(smraw + 4608);              // [32]
        const int lane = t & 63, w = t >> 6;
        const int half = lane >> 5, l31 = lane & 31;

        for (int u = u0; u < u1; ++u) {
            const int bh = u / 72, k0 = (u - bh * 72) * 32;
            half4_t kA = *(const half4_t*)(Kt + ((long)bh * LL + k0 + l31) * 8 + half * 4);
            const float4* qbase = (const float4*)(Qt + (long)bh * LL * 8);
            float4 pre = qbase[t];

            float16_t Dacc = {};
            for (int ch = 0; ch < 9; ++ch) {
                __syncthreads();
                *(float2*)&lQ[0][t][0] = make_float2(pre.x, pre.y);   // d 0..3
                *(float2*)&lQ[1][t][0] = make_float2(pre.z, pre.w);   // d 4..7
                __syncthreads();
                if (ch + 1 < 9) pre = qbase[(ch + 1) * 256 + t];
                #pragma unroll
                for (int T = 0; T < 2; ++T) {
                    half4_t qB = *(const half4_t*)&lQ[half][(2 * w + T) * 32 + l31][0];
                    float16_t S = __builtin_amdgcn_mfma_f32_32x32x8f16(kA, qB, (float16_t){}, 0, 0, 0);
                    #pragma unroll
                    for (int r = 0; r < 16; ++r) Dacc[r] += __builtin_amdgcn_exp2f(S[r]);
                }
            }
            #pragma unroll
            for (int r = 0; r < 16; ++r) {
                float v = Dacc[r];
                v += __shfl_xor(v, 1);  v += __shfl_xor(v, 2);  v += __shfl_xor(v, 4);
                v += __shfl_xor(v, 8);  v += __shfl_xor(v, 16);
                Dacc[r] = v;
            }
            if (l31 == 0) {
                #pragma unroll
                for (int r = 0; r < 16; ++r) {
                    int row = (r & 3) + 8 * (r >> 2) + 4 * half;
                    Dp[w][row] = Dacc[r];
                }
            }
            __syncthreads();
            if (t < 32) rDs[t] = 256.0f / (Dp[0][t] + Dp[1][t] + Dp[2][t] + Dp[3][t]);
            __syncthreads();
            {   // V2[bh][c][k0+kk] = V[k0+kk][c] * rDs[kk]
                int kk = t >> 3, c = t & 7;
                float v = (float)Vt[((long)bh * LL + k0 + kk) * 8 + c];
                V2[((long)bh * 8 + c) * LL + k0 + kk] = (_Float16)(v * rDs[kk]);
            }
            __syncthreads();
        }
    }
    grid_sync();

    // ===================== Phase 3: O' = V2 . 2^(Q'.K) ====================
    {
        const int u0 = (1152 * bid) / NB, u1 = (1152 * (bid + 1)) / NB;  // 2 units
        _Float16 (*lK)[64][4] = (_Float16(*)[64][4])smraw;          // [2][64][4] 1KB
        _Float16 (*lVt)[72]   = (_Float16(*)[72])(smraw + 1024);    // [8][72]
        const int lane = t & 63, w = t >> 6;
        const int half = lane >> 5, l31 = lane & 31;

        for (int u = u0; u < u1; ++u) {
            const int qb = u % 18, rem2 = u / 18;
            const int bh = rem2 & 15, s = rem2 >> 4;
            const int b = bh >> 3, h = bh & 7;
            const int q0 = qb * 128 + w * 32;

            half4_t qB = *(const half4_t*)(Qt + ((long)bh * LL + q0 + l31) * 8 + half * 4);
            const long ks0 = (long)s * 576;
            const float4*    kbase = (const float4*)(Kt + ((long)bh * LL + ks0) * 8);
            const _Float16*  vbase = V2 + (long)bh * 8 * LL + ks0;

            float4 preK, preV;
            if (t < 64) preK = kbase[t];
            else if (t < 128) {
                int c = (t - 64) >> 3, j8 = (t - 64) & 7;
                preV = *(const float4*)(vbase + (long)c * LL + j8 * 8);
            }

            float16_t O = {};
            for (int ch = 0; ch < 9; ++ch) {
                __syncthreads();
                if (t < 64) {
                    *(float2*)&lK[0][t][0] = make_float2(preK.x, preK.y);
                    *(float2*)&lK[1][t][0] = make_float2(preK.z, preK.w);
                } else if (t < 128) {
                    int c = (t - 64) >> 3, j8 = (t - 64) & 7;
                    *(float4*)&lVt[c][j8 * 8] = preV;
                }
                __syncthreads();
                if (ch + 1 < 9) {
                    if (t < 64) preK = kbase[(ch + 1) * 64 + t];
                    else if (t < 128) {
                        int c = (t - 64) >> 3, j8 = (t - 64) & 7;
                        preV = *(const float4*)(vbase + (long)c * LL + (ch + 1) * 64 + j8 * 8);
                    }
                }
                const int cl = l31 & 7;   // lanes 8..31 duplicate c rows (D rows >=8 unused)
                #pragma unroll
                for (int T = 0; T < 2; ++T) {
                    int kb = T * 32;
                    half4_t kA = *(const half4_t*)&lK[half][kb + l31][0];
                    float16_t S = __builtin_amdgcn_mfma_f32_32x32x8f16(kA, qB, (float16_t){}, 0, 0, 0);
                    #pragma unroll
                    for (int g = 0; g < 4; ++g) {
                        half2_t p0 = pk_f16(__builtin_amdgcn_exp2f(S[4 * g + 0]),
                                            __builtin_amdgcn_exp2f(S[4 * g + 1]));
                        half2_t p1 = pk_f16(__builtin_amdgcn_exp2f(S[4 * g + 2]),
                                            __builtin_amdgcn_exp2f(S[4 * g + 3]));
                        half4_t pB = __builtin_shufflevector(p0, p1, 0, 1, 2, 3);
                        half4_t vA = *(const half4_t*)&lVt[cl][kb + g * 8 + half * 4];
                        O = __builtin_amdgcn_mfma_f32_32x32x8f16(vA, pB, O, 0, 0, 0);
                    }
                }
            }
            // rows c<8 live in regs 0..3: c = r + 4*half; col q = l31
            float* otb = ot + (long)s * (2 * CCH * LL) + ((long)b * CCH + h * 8) * LL;
            #pragma unroll
            for (int r = 0; r < 4; ++r) {
                int c = r + 4 * half;
                otb[(long)c * LL + q0 + l31] = O[r] * (1.0f / 256.0f);
            }
            __syncthreads();
        }
    }
    grid_sync();

    // ==================== Phase 4: out = Wo.(sum ot) + bo =================
    {
        const int u0 = (144 * bid) / NB, u1 = (144 * (bid + 1)) / NB;  // 0..1 units
        float (*os)[32]  = (float(*)[32])smraw;
        float (*wsm)[64] = (float(*)[64])(smraw + 8192);
        const long SLAB = 2 * CCH * (long)LL;
        for (int u = u0; u < u1; ++u) {
            const int b = u / 72, l0 = (u % 72) * 32;
            const float* ob = ot + (long)b * CCH * LL;

            #pragma unroll
            for (int p = 0; p < 2; ++p) {
                int flat = (p * 256 + t) * 4;
                int cv = flat >> 5, l = flat & 31;
                long off = (long)cv * LL + l0 + l;
                float4 a = *(const float4*)&ob[off];
                #pragma unroll
                for (int s = 1; s < 4; ++s) {
                    float4 bb = *(const float4*)&ob[s * SLAB + off];
                    a.x += bb.x; a.y += bb.y; a.z += bb.z; a.w += bb.w;
                }
                *(float4*)&os[cv][l] = a;
            }
            #pragma unroll
            for (int p = 0; p < 4; ++p) {
                int flat = (p * 256 + t) * 4;
                int c = flat >> 6, l = flat & 63;
                *(float4*)&wsm[c][l] = *(const float4*)&Wo[flat];
            }
            __syncthreads();

            const int l  = t & 31;
            const int cg = t >> 5;
            float acc[8];
            #pragma unroll
            for (int j = 0; j < 8; ++j) acc[j] = 0.f;
            for (int cv = 0; cv < 64; ++cv) {
                float xv = os[cv][l];
                #pragma unroll
                for (int j = 0; j < 8; ++j) acc[j] = fmaf(wsm[cg * 8 + j][cv], xv, acc[j]);
            }
            #pragma unroll
            for (int j = 0; j < 8; ++j) {
                int co = cg * 8 + j;
                out[((long)b * CCH + co) * LL + l0 + l] = acc[j] + bo[co];
            }
        }
    }
}

// ---------------------------------------------------------------------------
extern "C" void kernel_launch(void* const* d_in, const int* in_sizes, int n_in,
                              void* d_out, int out_size, void* d_ws, size_t ws_size,
                              hipStream_t stream)
{
    const float* x  = (const float*)d_in[0];
    const float* Wq = (const float*)d_in[1];
    const float* bq = (const float*)d_in[2];
    const float* Wk = (const float*)d_in[3];
    const float* bk = (const float*)d_in[4];
    const float* Wv = (const float*)d_in[5];
    const float* bv = (const float*)d_in[6];
    const float* Wo = (const float*)d_in[7];
    const float* bo = (const float*)d_in[8];

    float* out  = (float*)d_out;          // [2][64][2304]
    float* qout = out + 294912;           // second tuple output: scaled q

    // ws: 4 f16 buffers (576KB ea) + 4 f32 ot slabs (4.7MB) = 7.08 MB
    _Float16* Qt = (_Float16*)d_ws;       // [16][2304][8] f16, * log2e*d^-0.5
    _Float16* Kt = Qt + 294912;           // [16][2304][8] f16
    _Float16* Vt = Kt + 294912;           // [16][2304][8] f16 (raw V)
    _Float16* V2 = Vt + 294912;           // [16][8][2304] f16 = V^T * 256/D
    float*    ot = (float*)(V2 + 294912); // [4][2][64][2304] f32 partial slabs

    k_fused<<<dim3(NB), 256, 0, stream>>>(x, Wq, bq, Wk, bk, Wv, bv, Wo, bo,
                                          qout, out, Qt, Kt, Vt, V2, ot);
}